// Round 6
// baseline (235.158 us; speedup 1.0000x reference)
//
#include <hip/hip_runtime.h>

// GCN 2-layer forward, fp32 in/out, fp16 gather tables. Build: 2-pass MSD
// radix sort by target node -> PADDED CSR (pad to mult of 16, pads -> row n
// of zeroed table; zero-degree nodes pse=(0,0), masked out). Aggregate: one
// wave per TWO nodes, 16 lanes per 32 B fp16 row, scalar srcs loads, 2-deep
// register rotation (16 gathers + 8 srcs in flight), per-node fmaf masks.
// XCD pass-pinning: lo-table blocks on XCDs 0-3, hi on 4-7; contiguous bip
// range per XCD. NEW r18: (1) cooperative table warm — each block streams a
// 4 KB slice of its pass's table (coalesced int4) so each XCD's 3.2 MB
// table is L2-resident via streaming, not demand-random misses; (2) non-
// temporal srcs loads + out stores so streams don't evict the table.
// History: r12 fp16 tables; r13 tail-split regressed; r14 split tables
// (FETCH 101->29/pass, time flat); r15 2-deep rotation; r16 2 nodes/wave +
// fused lo/hi = 53.8us (25 misses/CU concurrency cap); r17 3-deep + dummy
// blocks regressed (VALU up, srcs up). r18 attacks miss COUNT not depth.

#define WAVE 64
#define BN2 512           // nodes per bucket (9 bits local col)
#define NBMAX 256         // max coarse buckets (N <= 131072)
#define CHUNK 8192        // edges per partition block

typedef _Float16 f16;

// ---- bucket count: global histogram of col>>9 ----
__global__ void bucket_count_kernel(const int* __restrict__ col, int* __restrict__ gcnt,
                                    int E, int nb) {
    __shared__ int h[NBMAX];
    for (int i = threadIdx.x; i < nb; i += blockDim.x) h[i] = 0;
    __syncthreads();
    for (int e = blockIdx.x * blockDim.x + threadIdx.x; e < E; e += gridDim.x * blockDim.x)
        atomicAdd(&h[col[e] >> 9], 1);
    __syncthreads();
    for (int i = threadIdx.x; i < nb; i += blockDim.x)
        if (h[i]) atomicAdd(&gcnt[i], h[i]);
}

// ---- exclusive scan of bucket counts -> bptr[nb+1], init gcursor/gpcur,
//      zero the dummy gather rows (row N of each fp16 table) ----
__global__ void bucket_scan_kernel(const int* __restrict__ cnt, int* __restrict__ bptr,
                                   int* __restrict__ gcur, int nb, int* __restrict__ gpcur,
                                   f16* __restrict__ hlo, f16* __restrict__ hhi,
                                   f16* __restrict__ h2t, int nzr) {
    int lane = threadIdx.x;  // single wave
    if (lane == 0) gpcur[0] = 0;
    if (lane < 16)      hlo[(size_t)nzr * 16 + lane]        = (f16)0.f;
    else if (lane < 32) hhi[(size_t)nzr * 16 + (lane - 16)] = (f16)0.f;
    else if (lane < 48) h2t[(size_t)nzr * 16 + (lane - 32)] = (f16)0.f;
    int carry = 0;
    for (int base = 0; base < nb; base += WAVE) {
        int i = base + lane;
        int orig = (i < nb) ? cnt[i] : 0;
        int v = orig;
#pragma unroll
        for (int off = 1; off < WAVE; off <<= 1) {
            int t = __shfl_up(v, off, WAVE);
            if (lane >= off) v += t;
        }
        if (i < nb) { bptr[i] = carry + v - orig; gcur[i] = carry + v - orig; }
        carry += __shfl(v, WAVE - 1, WAVE);
    }
    if (lane == 0) bptr[nb] = carry;
}

// ---- pass 1: LDS-binned partition of packed (src<<9 | local_col) ----
__global__ void __launch_bounds__(512)
partition_kernel(const int* __restrict__ row, const int* __restrict__ col,
                 int* __restrict__ gcursor, unsigned* __restrict__ packed,
                 int E, int nb) {
    __shared__ int hist[NBMAX], excl[NBMAX], cursor[NBMAX], baseoff[NBMAX];
    __shared__ unsigned stage[CHUNK];
    int chunk0 = blockIdx.x * CHUNK;
    int cn = E - chunk0; if (cn > CHUNK) cn = CHUNK;
    for (int i = threadIdx.x; i < nb; i += blockDim.x) hist[i] = 0;
    __syncthreads();
    for (int i = threadIdx.x; i < cn; i += blockDim.x)
        atomicAdd(&hist[col[chunk0 + i] >> 9], 1);
    __syncthreads();
    if (threadIdx.x < WAVE) {
        int lane = threadIdx.x, carry = 0;
        for (int base = 0; base < nb; base += WAVE) {
            int i = base + lane;
            int orig = (i < nb) ? hist[i] : 0;
            int v = orig;
#pragma unroll
            for (int off = 1; off < WAVE; off <<= 1) {
                int t = __shfl_up(v, off, WAVE);
                if (lane >= off) v += t;
            }
            if (i < nb) { excl[i] = carry + v - orig; cursor[i] = carry + v - orig; }
            carry += __shfl(v, WAVE - 1, WAVE);
        }
    }
    __syncthreads();
    for (int b = threadIdx.x; b < nb; b += blockDim.x) {
        int c = hist[b];
        baseoff[b] = c ? atomicAdd(&gcursor[b], c) : 0;
    }
    __syncthreads();
    for (int i = threadIdx.x; i < cn; i += blockDim.x) {
        int c = col[chunk0 + i], r = row[chunk0 + i];
        int b = c >> 9;
        int pos = atomicAdd(&cursor[b], 1);
        stage[pos] = ((unsigned)r << 9) | (unsigned)(c & (BN2 - 1));
    }
    __syncthreads();
    int wave = threadIdx.x >> 6, lane = threadIdx.x & 63, nw = blockDim.x >> 6;
    for (int b = wave; b < nb; b += nw) {
        int c = hist[b]; if (!c) continue;
        int s = excl[b], d = baseoff[b];
        for (int k = lane; k < c; k += WAVE) packed[d + k] = stage[s + k];
    }
}

// ---- pass 2: per-bucket sort by local node -> padded srcs, pse, dinv.
//      Per-node region padded to multiple of 16; pads point at row n (zeros).
//      Zero-degree nodes get pse=(0,0). Bucket regions via global cursor. ----
__global__ void __launch_bounds__(512)
sort_kernel(const int* __restrict__ bptr, const unsigned* __restrict__ packed,
            int* __restrict__ srcs, int2* __restrict__ pse,
            float* __restrict__ dinv, int* __restrict__ gpcur,
            int n, int nb, int E) {
    __shared__ int hist[BN2], pex[BN2], cur[BN2];
    __shared__ int pbase_s;
    int b = blockIdx.x;
    int start = bptr[b], end = bptr[b + 1];
    for (int i = threadIdx.x; i < BN2; i += blockDim.x) { hist[i] = 0; cur[i] = 0; }
    __syncthreads();
    for (int k = start + threadIdx.x; k < end; k += blockDim.x)
        atomicAdd(&hist[packed[k] & (BN2 - 1)], 1);
    __syncthreads();
    if (threadIdx.x < WAVE) {   // scan of PADDED degrees over 512 locals
        int lane = threadIdx.x, carry = 0;
#pragma unroll
        for (int base = 0; base < BN2; base += WAVE) {
            int i = base + lane;
            int pd = (hist[i] + 15) & ~15;
            int v = pd;
#pragma unroll
            for (int off = 1; off < WAVE; off <<= 1) {
                int t = __shfl_up(v, off, WAVE);
                if (lane >= off) v += t;
            }
            pex[i] = carry + v - pd;
            carry += __shfl(v, WAVE - 1, WAVE);
        }
        if (lane == 0) pbase_s = atomicAdd(gpcur, carry);
    }
    __syncthreads();
    int pbase = pbase_s;
    for (int i = threadIdx.x; i < BN2; i += blockDim.x) {
        int node = b * BN2 + i;
        if (node < n) {
            int d = hist[i], pd = (d + 15) & ~15;
            int ps = pbase + pex[i];
            pse[node]  = d ? make_int2(ps, ps + pd) : make_int2(0, 0);
            dinv[node] = d ? rsqrtf((float)d) : 0.f;
            for (int k = d; k < pd; ++k) srcs[ps + k] = n;   // dummy zero-row
        }
    }
    __syncthreads();
    for (int k = start + threadIdx.x; k < end; k += blockDim.x) {
        unsigned p = packed[k];
        int lc = p & (BN2 - 1);
        int pos = atomicAdd(&cur[lc], 1);
        srcs[pbase + pex[lc] + pos] = (int)(p >> 9);
    }
}

// ---- dense: h[n,OUTC] = fp16( (x[n,INC] @ W) * dinv[n] ).
//      Thread = 2 nodes x 4 j. W^T in LDS, stride INC+4 (conflict-free).
//      SPLIT: route cols 0-15 -> hlo, 16-31 -> hhi (16-wide fp16 rows). ----
template <int INC, int OUTC, int JT, bool SPLIT>
__global__ void __launch_bounds__(256, 4)
dense_kernel(const float* __restrict__ x, const float* __restrict__ W,
             const float* __restrict__ dinv, f16* __restrict__ hlo,
             f16* __restrict__ hhi, int n) {
    const int LSTR = INC + 4;
    const int SP   = 256 / JT;     // node slots (pairs) per block
    const int NT   = SP * 2;       // nodes per block
    __shared__ float Wt[OUTC * LSTR];
    for (int i = threadIdx.x; i < INC * OUTC; i += 256) {
        int k = i / OUTC, j = i % OUTC;
        Wt[j * LSTR + k] = W[i];
    }
    __syncthreads();
    const int jg = threadIdx.x % JT;
    const int sp = threadIdx.x / JT;
    int base = blockIdx.x * NT;
    int n0 = base + sp;
    int n1 = base + sp + SP;
    int n0c = n0 < n ? n0 : n - 1;   // clamp reads, guard writes
    int n1c = n1 < n ? n1 : n - 1;
    const float4* xr0 = (const float4*)(x + (size_t)n0c * INC);
    const float4* xr1 = (const float4*)(x + (size_t)n1c * INC);
    float a[2][4] = {{0.f, 0.f, 0.f, 0.f}, {0.f, 0.f, 0.f, 0.f}};
#pragma unroll 4
    for (int k4 = 0; k4 < INC / 4; ++k4) {
        float4 v0 = xr0[k4];
        float4 v1 = xr1[k4];
#pragma unroll
        for (int u = 0; u < 4; ++u) {
            float4 w = *(const float4*)(Wt + (jg + u * JT) * LSTR + 4 * k4);
            a[0][u] = fmaf(v0.x, w.x, fmaf(v0.y, w.y, fmaf(v0.z, w.z, fmaf(v0.w, w.w, a[0][u]))));
            a[1][u] = fmaf(v1.x, w.x, fmaf(v1.y, w.y, fmaf(v1.z, w.z, fmaf(v1.w, w.w, a[1][u]))));
        }
    }
#pragma unroll
    for (int pair = 0; pair < 2; ++pair) {
        int nn = pair ? n1 : n0;
        if (nn < n) {
            float d = dinv[nn];
#pragma unroll
            for (int u = 0; u < 4; ++u) {
                int c = jg + u * JT;
                f16* t;
                if (SPLIT) t = (c < 16) ? (hlo + (size_t)nn * 16 + c)
                               : (hhi + (size_t)nn * 16 + (c - 16));
                else       t = hlo + (size_t)nn * OUTC + c;
                *t = (f16)(a[pair][u] * d);
            }
        }
    }
}

// ---- aggregate: one wave per TWO nodes; 16 lanes per 32 B fp16 row;
//      scalar srcs (nt), 2-deep rotation, per-node fmaf masks. PIN: grid
//      must be %8; XCD x gets contiguous bid range; XCDs 0-3 -> lo pass,
//      4-7 -> hi. WARM: each block streams one 4 KB coalesced slice of its
//      pass's table into L2 before the gather loop. ----
#define NTL(p) __builtin_nontemporal_load(p)
#define GLD(s) (*(const f16*)(hb + (((unsigned)(s) << 5) + j2)))

template <bool RELU, bool PIN>
__global__ void __launch_bounds__(256)
csr_agg16x2_kernel(const int2* __restrict__ pse, const int* __restrict__ srcs,
                   const float* __restrict__ dinv, const f16* __restrict__ tlo,
                   const f16* __restrict__ thi, const float* __restrict__ bias,
                   float* __restrict__ out, int ostride, int hg, int n, int tailidx) {
    int bid = blockIdx.x;
    if (PIN) {
        int per = (int)(gridDim.x >> 3);     // blocks per XCD (grid % 8 == 0)
        bid = (bid & 7) * per + (bid >> 3);  // contiguous range per XCD
    }
    int pass = (bid >= hg) ? 1 : 0;
    const f16* hs = pass ? thi : tlo;
    int ocol = pass << 4;
    int bip = bid - pass * hg;
    if (tailidx >= 0 && blockIdx.x == 0 && threadIdx.x == 0) out[tailidx] = 0.f;
    // cooperative table warm: 4 KB coalesced slice per block (per-XCD bip
    // ranges are contiguous -> every XCD streams its whole table)
    {
        int tq  = (n + 1) * 2;               // table size in int4 units
        int nsl = (tq + 255) >> 8;           // 4 KB slices
        int idx4 = (bip % nsl) * 256 + (int)threadIdx.x;
        if (idx4 < tq) {
            int4 wv = ((const int4*)hs)[idx4];
            asm volatile("" :: "v"(wv.x), "v"(wv.y), "v"(wv.z), "v"(wv.w));
        }
    }
    int lane = threadIdx.x & 63;
    int wid  = threadIdx.x >> 6;
    int j  = lane & 15;
    int eo = lane >> 4;           // 0..3
    int n0 = (bip * 4 + wid) * 2;
    if (n0 >= n) return;
    int n1 = n0 + 1;
    bool v1 = n1 < n;
    int4 se = *(const int4*)(pse + n0);      // pse[n0], pse[n1]
    int nb0 = (se.y - se.x) >> 4;
    int nb1 = v1 ? ((se.w - se.z) >> 4) : 0;
    float dv0 = dinv[n0];
    float dv1 = v1 ? dinv[n1] : 0.f;
    float bj = bias[ocol + j];
    size_t ob0 = (size_t)n0 * ostride + ocol + j;
    size_t ob1 = (size_t)n1 * ostride + ocol + j;
    int MAXB = nb0 > nb1 ? nb0 : nb1;
    if (MAXB == 0) {
        float v = bj;
        if (RELU) v = v > 0.f ? v : 0.f;
        if (eo == 0) __builtin_nontemporal_store(v, &out[ob0]);
        else if (eo == 1 && v1) __builtin_nontemporal_store(v, &out[ob1]);
        return;
    }
    const unsigned j2 = (unsigned)(j << 1);
    const char* hb = (const char*)hs;
    const int* p0 = srcs + se.x + eo;
    const int* p1 = srcs + (v1 ? se.z : se.x) + eo;
    int nc0 = nb0 > 1 ? nb0 : 1;
    int nc1 = nb1 > 1 ? nb1 : 1;
    // prologue: block-0 srcs, block-0 gathers, block-1 srcs (clamped)
    int a0 = NTL(p0), a1 = NTL(p0 + 4), a2 = NTL(p0 + 8), a3 = NTL(p0 + 12);
    int a4 = NTL(p1), a5 = NTL(p1 + 4), a6 = NTL(p1 + 8), a7 = NTL(p1 + 12);
    f16 h0 = GLD(a0), h1 = GLD(a1), h2 = GLD(a2), h3 = GLD(a3);
    f16 h4 = GLD(a4), h5 = GLD(a5), h6 = GLD(a6), h7 = GLD(a7);
    const int* q0 = p0 + (nc0 > 1 ? 16 : 0);
    const int* q1 = p1 + (nc1 > 1 ? 16 : 0);
    int b0 = NTL(q0), b1 = NTL(q0 + 4), b2 = NTL(q0 + 8), b3 = NTL(q0 + 12);
    int b4 = NTL(q1), b5 = NTL(q1 + 4), b6 = NTL(q1 + 8), b7 = NTL(q1 + 12);
    float acc0 = 0.f, acc1 = 0.f, acc2 = 0.f, acc3 = 0.f;
    for (int b = 0; b < MAXB - 1; ++b) {
        // gathers for block b+1
        f16 g0 = GLD(b0), g1 = GLD(b1), g2 = GLD(b2), g3 = GLD(b3);
        f16 g4 = GLD(b4), g5 = GLD(b5), g6 = GLD(b6), g7 = GLD(b7);
        // srcs for block b+2 (clamped per node)
        int x0 = (b + 2) < nc0 ? (b + 2) : nc0 - 1;
        int x1 = (b + 2) < nc1 ? (b + 2) : nc1 - 1;
        const int* r0 = p0 + x0 * 16;
        const int* r1 = p1 + x1 * 16;
        int t0 = NTL(r0), t1 = NTL(r0 + 4), t2 = NTL(r0 + 8), t3 = NTL(r0 + 12);
        int t4 = NTL(r1), t5 = NTL(r1 + 4), t6 = NTL(r1 + 8), t7 = NTL(r1 + 12);
        // consume block b (masked per node)
        float m0 = b < nb0 ? 1.f : 0.f;
        float m1 = b < nb1 ? 1.f : 0.f;
        acc0 = fmaf(m0, (float)h0, acc0);
        acc1 = fmaf(m0, (float)h1, acc1);
        acc0 = fmaf(m0, (float)h2, acc0);
        acc1 = fmaf(m0, (float)h3, acc1);
        acc2 = fmaf(m1, (float)h4, acc2);
        acc3 = fmaf(m1, (float)h5, acc3);
        acc2 = fmaf(m1, (float)h6, acc2);
        acc3 = fmaf(m1, (float)h7, acc3);
        h0 = g0; h1 = g1; h2 = g2; h3 = g3;
        h4 = g4; h5 = g5; h6 = g6; h7 = g7;
        b0 = t0; b1 = t1; b2 = t2; b3 = t3;
        b4 = t4; b5 = t5; b6 = t6; b7 = t7;
    }
    {   // epilogue: block MAXB-1
        float m0 = (MAXB - 1) < nb0 ? 1.f : 0.f;
        float m1 = (MAXB - 1) < nb1 ? 1.f : 0.f;
        acc0 = fmaf(m0, (float)h0, acc0);
        acc1 = fmaf(m0, (float)h1, acc1);
        acc0 = fmaf(m0, (float)h2, acc0);
        acc1 = fmaf(m0, (float)h3, acc1);
        acc2 = fmaf(m1, (float)h4, acc2);
        acc3 = fmaf(m1, (float)h5, acc3);
        acc2 = fmaf(m1, (float)h6, acc2);
        acc3 = fmaf(m1, (float)h7, acc3);
    }
    float accA = acc0 + acc1;  // node0
    float accB = acc2 + acc3;  // node1
    accA += __shfl_xor(accA, 16, WAVE);
    accA += __shfl_xor(accA, 32, WAVE);
    accB += __shfl_xor(accB, 16, WAVE);
    accB += __shfl_xor(accB, 32, WAVE);
    if (eo == 0) {
        float v = accA * dv0 + bj;
        if (RELU) v = v > 0.f ? v : 0.f;
        __builtin_nontemporal_store(v, &out[ob0]);
    } else if (eo == 1 && v1) {
        float v = accB * dv1 + bj;
        if (RELU) v = v > 0.f ? v : 0.f;
        __builtin_nontemporal_store(v, &out[ob1]);
    }
}

extern "C" void kernel_launch(void* const* d_in, const int* in_sizes, int n_in,
                              void* d_out, int out_size, void* d_ws, size_t ws_size,
                              hipStream_t stream) {
    const float* x  = (const float*)d_in[0];
    const int*   ei = (const int*)d_in[1];    // harness converts int64 -> int32
    const float* W1 = (const float*)d_in[2];
    const float* b1 = (const float*)d_in[3];
    const float* W2 = (const float*)d_in[4];
    const float* b2 = (const float*)d_in[5];

    const int IN_C = 128, HID = 32, OC = 16;
    const int N = in_sizes[0] / IN_C;       // 100000
    const int E = in_sizes[1] / 2;          // 3200000
    const int* row = ei;
    const int* col = ei + E;
    const int NB = (N + BN2 - 1) / BN2;     // 196 coarse buckets

    char* base = (char*)d_ws;
    size_t off = 0;
    auto carve = [&](size_t bytes) -> char* {
        char* p = base + off;
        off = (off + bytes + 255) & ~(size_t)255;
        return p;
    };
    int*      gcnt  = (int*)     carve((size_t)NB * 4);
    int*      bptr  = (int*)     carve((size_t)(NB + 1) * 4);
    int*      gcur  = (int*)     carve((size_t)NB * 4);
    int*      gpcur = (int*)     carve(8);
    float*    dinv  = (float*)   carve((size_t)N * 4);
    int2*     pse   = (int2*)    carve((size_t)(N + 2) * 8);
    unsigned* packed= (unsigned*)carve((size_t)E * 4);
    int*      srcsP = (int*)     carve(((size_t)E + (size_t)N * 32 + 256) * 4); // pads + slack
    f16*      hlo   = (f16*)     carve((size_t)(N + 1) * 16 * 2);  // layer1 cols 0-15 (+zero row)
    f16*      hhi   = (f16*)     carve((size_t)(N + 1) * 16 * 2);  // layer1 cols 16-31
    f16*      h2t   = (f16*)     carve((size_t)(N + 1) * 16 * 2);  // layer2 table
    float*    bufB  = (float*)   carve((size_t)N * HID * 4);       // relu(agg1), fp32
    (void)ws_size; (void)n_in;

    float* outp = (float*)d_out;

    // build: 2-pass coarse radix sort by target node -> padded CSR + dinv
    hipMemsetAsync(gcnt, 0, (size_t)NB * 4, stream);
    bucket_count_kernel<<<512, 256, 0, stream>>>(col, gcnt, E, NB);
    bucket_scan_kernel<<<1, 64, 0, stream>>>(gcnt, bptr, gcur, NB, gpcur, hlo, hhi, h2t, N);
    partition_kernel<<<(E + CHUNK - 1) / CHUNK, 512, 0, stream>>>(row, col, gcur, packed, E, NB);
    sort_kernel<<<NB, 512, 0, stream>>>(bptr, packed, srcsP, pse, dinv, gpcur, N, NB, E);

    int npb = 8;                               // 4 waves x 2 nodes per block
    int g2  = (N + npb - 1) / npb;             // blocks per pass (12500)
    int g2r = (g2 + 7) & ~7;                   // rounded so grids are % 8 (12504)

    // layer 1: {hlo,hhi} = fp16((x@W1)*dinv) ; bufB = relu(dinv*agg + b1)
    {
        const int NT = (256 / 8) * 2;  // 64 nodes per block
        dense_kernel<128, 32, 8, true><<<(N + NT - 1) / NT, 256, 0, stream>>>(x, W1, dinv, hlo, hhi, N);
        csr_agg16x2_kernel<true, true><<<2 * g2r, 256, 0, stream>>>(
            pse, srcsP, dinv, hlo, hhi, b1, bufB, HID, g2r, N, -1);
    }
    // layer 2: h2t = fp16((bufB@W2)*dinv) ; out = dinv*agg(h2t) + b2
    {
        const int NT = (256 / 4) * 2;  // 128 nodes per block
        dense_kernel<32, 16, 4, false><<<(N + NT - 1) / NT, 256, 0, stream>>>(bufB, W2, dinv, h2t, nullptr, N);
        int tailidx = (out_size > N * OC) ? (N * OC) : -1;
        csr_agg16x2_kernel<false, true><<<g2r, 256, 0, stream>>>(
            pse, srcsP, dinv, h2t, h2t, b2, outp, OC, g2r, N, tailidx);
    }
}

// Round 8
// 191.952 us; speedup vs baseline: 1.2251x; 1.2251x over previous
//
#include <hip/hip_runtime.h>

// GCN 2-layer forward, fp32 in/out, fp16 gather tables. Build: 2-pass MSD
// radix sort by target node -> PADDED CSR (pad to mult of 16, pads -> row n
// of zeroed table; zero-degree nodes pse=(0,0), masked out). Aggregate: one
// wave per TWO nodes, 16 lanes per 32 B fp16 row, 2-deep register rotation,
// per-node fmaf masks; srcs loaded as int4 (1 inst per node per step).
// History: r12 fp16 tables; r13 tail-split regressed (latency not VALU);
// r14 split tables (FETCH 101->29/pass, time flat); r15 2-deep rotation;
// r16 2 nodes/wave + fused lo/hi = 53.8us best; r17 3-deep+dummy+pin
// regressed (VALU); r18 warm+nt regressed 43% at LOWER fetch -> proved the
// bound is VMEM *instruction* throughput (~8cy/inst TA), not misses:
// time tracks inst count across r0/r4/r6, invariant to 3x traffic change.
// r19 (this, resubmit after infra failure): exact r16 body, srcs 8 scalar
// -> 2 int4 insts/step (16->10 VMEM/step). No pin, no warm, no nt.

#define WAVE 64
#define BN2 512           // nodes per bucket (9 bits local col)
#define NBMAX 256         // max coarse buckets (N <= 131072)
#define CHUNK 8192        // edges per partition block

typedef _Float16 f16;

// ---- bucket count: global histogram of col>>9 ----
__global__ void bucket_count_kernel(const int* __restrict__ col, int* __restrict__ gcnt,
                                    int E, int nb) {
    __shared__ int h[NBMAX];
    for (int i = threadIdx.x; i < nb; i += blockDim.x) h[i] = 0;
    __syncthreads();
    for (int e = blockIdx.x * blockDim.x + threadIdx.x; e < E; e += gridDim.x * blockDim.x)
        atomicAdd(&h[col[e] >> 9], 1);
    __syncthreads();
    for (int i = threadIdx.x; i < nb; i += blockDim.x)
        if (h[i]) atomicAdd(&gcnt[i], h[i]);
}

// ---- exclusive scan of bucket counts -> bptr[nb+1], init gcursor/gpcur,
//      zero the dummy gather rows (row N of each fp16 table) ----
__global__ void bucket_scan_kernel(const int* __restrict__ cnt, int* __restrict__ bptr,
                                   int* __restrict__ gcur, int nb, int* __restrict__ gpcur,
                                   f16* __restrict__ hlo, f16* __restrict__ hhi,
                                   f16* __restrict__ h2t, int nzr) {
    int lane = threadIdx.x;  // single wave
    if (lane == 0) gpcur[0] = 0;
    if (lane < 16)      hlo[(size_t)nzr * 16 + lane]        = (f16)0.f;
    else if (lane < 32) hhi[(size_t)nzr * 16 + (lane - 16)] = (f16)0.f;
    else if (lane < 48) h2t[(size_t)nzr * 16 + (lane - 32)] = (f16)0.f;
    int carry = 0;
    for (int base = 0; base < nb; base += WAVE) {
        int i = base + lane;
        int orig = (i < nb) ? cnt[i] : 0;
        int v = orig;
#pragma unroll
        for (int off = 1; off < WAVE; off <<= 1) {
            int t = __shfl_up(v, off, WAVE);
            if (lane >= off) v += t;
        }
        if (i < nb) { bptr[i] = carry + v - orig; gcur[i] = carry + v - orig; }
        carry += __shfl(v, WAVE - 1, WAVE);
    }
    if (lane == 0) bptr[nb] = carry;
}

// ---- pass 1: LDS-binned partition of packed (src<<9 | local_col) ----
__global__ void __launch_bounds__(512)
partition_kernel(const int* __restrict__ row, const int* __restrict__ col,
                 int* __restrict__ gcursor, unsigned* __restrict__ packed,
                 int E, int nb) {
    __shared__ int hist[NBMAX], excl[NBMAX], cursor[NBMAX], baseoff[NBMAX];
    __shared__ unsigned stage[CHUNK];
    int chunk0 = blockIdx.x * CHUNK;
    int cn = E - chunk0; if (cn > CHUNK) cn = CHUNK;
    for (int i = threadIdx.x; i < nb; i += blockDim.x) hist[i] = 0;
    __syncthreads();
    for (int i = threadIdx.x; i < cn; i += blockDim.x)
        atomicAdd(&hist[col[chunk0 + i] >> 9], 1);
    __syncthreads();
    if (threadIdx.x < WAVE) {
        int lane = threadIdx.x, carry = 0;
        for (int base = 0; base < nb; base += WAVE) {
            int i = base + lane;
            int orig = (i < nb) ? hist[i] : 0;
            int v = orig;
#pragma unroll
            for (int off = 1; off < WAVE; off <<= 1) {
                int t = __shfl_up(v, off, WAVE);
                if (lane >= off) v += t;
            }
            if (i < nb) { excl[i] = carry + v - orig; cursor[i] = carry + v - orig; }
            carry += __shfl(v, WAVE - 1, WAVE);
        }
    }
    __syncthreads();
    for (int b = threadIdx.x; b < nb; b += blockDim.x) {
        int c = hist[b];
        baseoff[b] = c ? atomicAdd(&gcursor[b], c) : 0;
    }
    __syncthreads();
    for (int i = threadIdx.x; i < cn; i += blockDim.x) {
        int c = col[chunk0 + i], r = row[chunk0 + i];
        int b = c >> 9;
        int pos = atomicAdd(&cursor[b], 1);
        stage[pos] = ((unsigned)r << 9) | (unsigned)(c & (BN2 - 1));
    }
    __syncthreads();
    int wave = threadIdx.x >> 6, lane = threadIdx.x & 63, nw = blockDim.x >> 6;
    for (int b = wave; b < nb; b += nw) {
        int c = hist[b]; if (!c) continue;
        int s = excl[b], d = baseoff[b];
        for (int k = lane; k < c; k += WAVE) packed[d + k] = stage[s + k];
    }
}

// ---- pass 2: per-bucket sort by local node -> padded srcs, pse, dinv.
//      Per-node region padded to multiple of 16; pads point at row n (zeros).
//      Zero-degree nodes get pse=(0,0). Bucket regions via global cursor. ----
__global__ void __launch_bounds__(512)
sort_kernel(const int* __restrict__ bptr, const unsigned* __restrict__ packed,
            int* __restrict__ srcs, int2* __restrict__ pse,
            float* __restrict__ dinv, int* __restrict__ gpcur,
            int n, int nb, int E) {
    __shared__ int hist[BN2], pex[BN2], cur[BN2];
    __shared__ int pbase_s;
    int b = blockIdx.x;
    int start = bptr[b], end = bptr[b + 1];
    for (int i = threadIdx.x; i < BN2; i += blockDim.x) { hist[i] = 0; cur[i] = 0; }
    __syncthreads();
    for (int k = start + threadIdx.x; k < end; k += blockDim.x)
        atomicAdd(&hist[packed[k] & (BN2 - 1)], 1);
    __syncthreads();
    if (threadIdx.x < WAVE) {   // scan of PADDED degrees over 512 locals
        int lane = threadIdx.x, carry = 0;
#pragma unroll
        for (int base = 0; base < BN2; base += WAVE) {
            int i = base + lane;
            int pd = (hist[i] + 15) & ~15;
            int v = pd;
#pragma unroll
            for (int off = 1; off < WAVE; off <<= 1) {
                int t = __shfl_up(v, off, WAVE);
                if (lane >= off) v += t;
            }
            pex[i] = carry + v - pd;
            carry += __shfl(v, WAVE - 1, WAVE);
        }
        if (lane == 0) pbase_s = atomicAdd(gpcur, carry);
    }
    __syncthreads();
    int pbase = pbase_s;
    for (int i = threadIdx.x; i < BN2; i += blockDim.x) {
        int node = b * BN2 + i;
        if (node < n) {
            int d = hist[i], pd = (d + 15) & ~15;
            int ps = pbase + pex[i];
            pse[node]  = d ? make_int2(ps, ps + pd) : make_int2(0, 0);
            dinv[node] = d ? rsqrtf((float)d) : 0.f;
            for (int k = d; k < pd; ++k) srcs[ps + k] = n;   // dummy zero-row
        }
    }
    __syncthreads();
    for (int k = start + threadIdx.x; k < end; k += blockDim.x) {
        unsigned p = packed[k];
        int lc = p & (BN2 - 1);
        int pos = atomicAdd(&cur[lc], 1);
        srcs[pbase + pex[lc] + pos] = (int)(p >> 9);
    }
}

// ---- dense: h[n,OUTC] = fp16( (x[n,INC] @ W) * dinv[n] ).
//      Thread = 2 nodes x 4 j. W^T in LDS, stride INC+4 (conflict-free).
//      SPLIT: route cols 0-15 -> hlo, 16-31 -> hhi (16-wide fp16 rows). ----
template <int INC, int OUTC, int JT, bool SPLIT>
__global__ void __launch_bounds__(256, 4)
dense_kernel(const float* __restrict__ x, const float* __restrict__ W,
             const float* __restrict__ dinv, f16* __restrict__ hlo,
             f16* __restrict__ hhi, int n) {
    const int LSTR = INC + 4;
    const int SP   = 256 / JT;     // node slots (pairs) per block
    const int NT   = SP * 2;       // nodes per block
    __shared__ float Wt[OUTC * LSTR];
    for (int i = threadIdx.x; i < INC * OUTC; i += 256) {
        int k = i / OUTC, j = i % OUTC;
        Wt[j * LSTR + k] = W[i];
    }
    __syncthreads();
    const int jg = threadIdx.x % JT;
    const int sp = threadIdx.x / JT;
    int base = blockIdx.x * NT;
    int n0 = base + sp;
    int n1 = base + sp + SP;
    int n0c = n0 < n ? n0 : n - 1;   // clamp reads, guard writes
    int n1c = n1 < n ? n1 : n - 1;
    const float4* xr0 = (const float4*)(x + (size_t)n0c * INC);
    const float4* xr1 = (const float4*)(x + (size_t)n1c * INC);
    float a[2][4] = {{0.f, 0.f, 0.f, 0.f}, {0.f, 0.f, 0.f, 0.f}};
#pragma unroll 4
    for (int k4 = 0; k4 < INC / 4; ++k4) {
        float4 v0 = xr0[k4];
        float4 v1 = xr1[k4];
#pragma unroll
        for (int u = 0; u < 4; ++u) {
            float4 w = *(const float4*)(Wt + (jg + u * JT) * LSTR + 4 * k4);
            a[0][u] = fmaf(v0.x, w.x, fmaf(v0.y, w.y, fmaf(v0.z, w.z, fmaf(v0.w, w.w, a[0][u]))));
            a[1][u] = fmaf(v1.x, w.x, fmaf(v1.y, w.y, fmaf(v1.z, w.z, fmaf(v1.w, w.w, a[1][u]))));
        }
    }
#pragma unroll
    for (int pair = 0; pair < 2; ++pair) {
        int nn = pair ? n1 : n0;
        if (nn < n) {
            float d = dinv[nn];
#pragma unroll
            for (int u = 0; u < 4; ++u) {
                int c = jg + u * JT;
                f16* t;
                if (SPLIT) t = (c < 16) ? (hlo + (size_t)nn * 16 + c)
                               : (hhi + (size_t)nn * 16 + (c - 16));
                else       t = hlo + (size_t)nn * OUTC + c;
                *t = (f16)(a[pair][u] * d);
            }
        }
    }
}

// ---- aggregate: one wave per TWO nodes; 16 lanes per 32 B fp16 row.
//      Per block-step per node: ONE int4 srcs load (lane-group eo reads
//      srcs[b*16+eo*4..+3]; gather inst u consumes component u -> still 4
//      unique rows/inst) + 4 gather insts. 2-deep rotation (16 gathers +
//      2 srcs in flight at the consume-wait), per-node fmaf masks. ----
#define GLD(s) (*(const f16*)(hb + (((unsigned)(s) << 5) + j2)))

template <bool RELU>
__global__ void __launch_bounds__(256)
csr_agg16x2_kernel(const int2* __restrict__ pse, const int* __restrict__ srcs,
                   const float* __restrict__ dinv, const f16* __restrict__ tlo,
                   const f16* __restrict__ thi, const float* __restrict__ bias,
                   float* __restrict__ out, int ostride, int hg, int n, int tailidx) {
    int bid = blockIdx.x;
    int pass = (bid >= hg) ? 1 : 0;
    const f16* hs = pass ? thi : tlo;
    int ocol = pass << 4;
    int bip = bid - pass * hg;
    int lane = threadIdx.x & 63;
    int wid  = threadIdx.x >> 6;
    int j  = lane & 15;
    int eo = lane >> 4;           // 0..3
    if (tailidx >= 0 && bid == 0 && threadIdx.x == 0) out[tailidx] = 0.f;
    int n0 = (bip * 4 + wid) * 2;
    if (n0 >= n) return;
    int n1 = n0 + 1;
    bool v1 = n1 < n;
    int4 se = *(const int4*)(pse + n0);      // pse[n0], pse[n1]
    int nb0 = (se.y - se.x) >> 4;
    int nb1 = v1 ? ((se.w - se.z) >> 4) : 0;
    float dv0 = dinv[n0];
    float dv1 = v1 ? dinv[n1] : 0.f;
    float bj = bias[ocol + j];
    size_t ob0 = (size_t)n0 * ostride + ocol + j;
    size_t ob1 = (size_t)n1 * ostride + ocol + j;
    int MAXB = nb0 > nb1 ? nb0 : nb1;
    if (MAXB == 0) {
        float v = bj;
        if (RELU) v = v > 0.f ? v : 0.f;
        if (eo == 0) out[ob0] = v;
        else if (eo == 1 && v1) out[ob1] = v;
        return;
    }
    const unsigned j2 = (unsigned)(j << 1);
    const char* hb = (const char*)hs;
    // region starts are multiples of 16 ints -> 64 B aligned int4 access
    const int4* P0 = (const int4*)(srcs + se.x) + eo;
    const int4* P1 = (const int4*)(srcs + (v1 ? se.z : se.x)) + eo;
    int nc0 = nb0 > 1 ? nb0 : 1;
    int nc1 = nb1 > 1 ? nb1 : 1;
    // prologue: block-0 srcs, block-0 gathers, block-1 srcs (clamped)
    int4 sA0 = P0[0];
    int4 sA1 = P1[0];
    f16 h0 = GLD(sA0.x), h1 = GLD(sA0.y), h2 = GLD(sA0.z), h3 = GLD(sA0.w);
    f16 h4 = GLD(sA1.x), h5 = GLD(sA1.y), h6 = GLD(sA1.z), h7 = GLD(sA1.w);
    int4 sB0 = P0[(nc0 > 1 ? 1 : 0) * 4];
    int4 sB1 = P1[(nc1 > 1 ? 1 : 0) * 4];
    float acc0 = 0.f, acc1 = 0.f, acc2 = 0.f, acc3 = 0.f;
    for (int b = 0; b < MAXB - 1; ++b) {
        // gathers for block b+1
        f16 g0 = GLD(sB0.x), g1 = GLD(sB0.y), g2 = GLD(sB0.z), g3 = GLD(sB0.w);
        f16 g4 = GLD(sB1.x), g5 = GLD(sB1.y), g6 = GLD(sB1.z), g7 = GLD(sB1.w);
        // srcs for block b+2 (clamped per node), one int4 per node
        int x0 = (b + 2) < nc0 ? (b + 2) : nc0 - 1;
        int x1 = (b + 2) < nc1 ? (b + 2) : nc1 - 1;
        int4 t0 = P0[x0 * 4];
        int4 t1 = P1[x1 * 4];
        // consume block b (masked per node)
        float m0 = b < nb0 ? 1.f : 0.f;
        float m1 = b < nb1 ? 1.f : 0.f;
        acc0 = fmaf(m0, (float)h0, acc0);
        acc1 = fmaf(m0, (float)h1, acc1);
        acc0 = fmaf(m0, (float)h2, acc0);
        acc1 = fmaf(m0, (float)h3, acc1);
        acc2 = fmaf(m1, (float)h4, acc2);
        acc3 = fmaf(m1, (float)h5, acc3);
        acc2 = fmaf(m1, (float)h6, acc2);
        acc3 = fmaf(m1, (float)h7, acc3);
        h0 = g0; h1 = g1; h2 = g2; h3 = g3;
        h4 = g4; h5 = g5; h6 = g6; h7 = g7;
        sB0 = t0; sB1 = t1;
    }
    {   // epilogue: block MAXB-1
        float m0 = (MAXB - 1) < nb0 ? 1.f : 0.f;
        float m1 = (MAXB - 1) < nb1 ? 1.f : 0.f;
        acc0 = fmaf(m0, (float)h0, acc0);
        acc1 = fmaf(m0, (float)h1, acc1);
        acc0 = fmaf(m0, (float)h2, acc0);
        acc1 = fmaf(m0, (float)h3, acc1);
        acc2 = fmaf(m1, (float)h4, acc2);
        acc3 = fmaf(m1, (float)h5, acc3);
        acc2 = fmaf(m1, (float)h6, acc2);
        acc3 = fmaf(m1, (float)h7, acc3);
    }
    float accA = acc0 + acc1;  // node0
    float accB = acc2 + acc3;  // node1
    accA += __shfl_xor(accA, 16, WAVE);
    accA += __shfl_xor(accA, 32, WAVE);
    accB += __shfl_xor(accB, 16, WAVE);
    accB += __shfl_xor(accB, 32, WAVE);
    if (eo == 0) {
        float v = accA * dv0 + bj;
        if (RELU) v = v > 0.f ? v : 0.f;
        out[ob0] = v;
    } else if (eo == 1 && v1) {
        float v = accB * dv1 + bj;
        if (RELU) v = v > 0.f ? v : 0.f;
        out[ob1] = v;
    }
}

extern "C" void kernel_launch(void* const* d_in, const int* in_sizes, int n_in,
                              void* d_out, int out_size, void* d_ws, size_t ws_size,
                              hipStream_t stream) {
    const float* x  = (const float*)d_in[0];
    const int*   ei = (const int*)d_in[1];    // harness converts int64 -> int32
    const float* W1 = (const float*)d_in[2];
    const float* b1 = (const float*)d_in[3];
    const float* W2 = (const float*)d_in[4];
    const float* b2 = (const float*)d_in[5];

    const int IN_C = 128, HID = 32, OC = 16;
    const int N = in_sizes[0] / IN_C;       // 100000
    const int E = in_sizes[1] / 2;          // 3200000
    const int* row = ei;
    const int* col = ei + E;
    const int NB = (N + BN2 - 1) / BN2;     // 196 coarse buckets

    char* base = (char*)d_ws;
    size_t off = 0;
    auto carve = [&](size_t bytes) -> char* {
        char* p = base + off;
        off = (off + bytes + 255) & ~(size_t)255;
        return p;
    };
    int*      gcnt  = (int*)     carve((size_t)NB * 4);
    int*      bptr  = (int*)     carve((size_t)(NB + 1) * 4);
    int*      gcur  = (int*)     carve((size_t)NB * 4);
    int*      gpcur = (int*)     carve(8);
    float*    dinv  = (float*)   carve((size_t)N * 4);
    int2*     pse   = (int2*)    carve((size_t)(N + 2) * 8);
    unsigned* packed= (unsigned*)carve((size_t)E * 4);
    int*      srcsP = (int*)     carve(((size_t)E + (size_t)N * 32 + 256) * 4); // pads + slack
    f16*      hlo   = (f16*)     carve((size_t)(N + 1) * 16 * 2);  // layer1 cols 0-15 (+zero row)
    f16*      hhi   = (f16*)     carve((size_t)(N + 1) * 16 * 2);  // layer1 cols 16-31
    f16*      h2t   = (f16*)     carve((size_t)(N + 1) * 16 * 2);  // layer2 table
    float*    bufB  = (float*)   carve((size_t)N * HID * 4);       // relu(agg1), fp32
    (void)ws_size; (void)n_in;

    float* outp = (float*)d_out;

    // build: 2-pass coarse radix sort by target node -> padded CSR + dinv
    hipMemsetAsync(gcnt, 0, (size_t)NB * 4, stream);
    bucket_count_kernel<<<512, 256, 0, stream>>>(col, gcnt, E, NB);
    bucket_scan_kernel<<<1, 64, 0, stream>>>(gcnt, bptr, gcur, NB, gpcur, hlo, hhi, h2t, N);
    partition_kernel<<<(E + CHUNK - 1) / CHUNK, 512, 0, stream>>>(row, col, gcur, packed, E, NB);
    sort_kernel<<<NB, 512, 0, stream>>>(bptr, packed, srcsP, pse, dinv, gpcur, N, NB, E);

    int npb = 8;                         // 4 waves x 2 nodes per block
    int g2  = (N + npb - 1) / npb;       // 12500 blocks per pass

    // layer 1: {hlo,hhi} = fp16((x@W1)*dinv) ; bufB = relu(dinv*agg + b1)
    {
        const int NT = (256 / 8) * 2;  // 64 nodes per block
        dense_kernel<128, 32, 8, true><<<(N + NT - 1) / NT, 256, 0, stream>>>(x, W1, dinv, hlo, hhi, N);
        csr_agg16x2_kernel<true><<<2 * g2, 256, 0, stream>>>(
            pse, srcsP, dinv, hlo, hhi, b1, bufB, HID, g2, N, -1);
    }
    // layer 2: h2t = fp16((bufB@W2)*dinv) ; out = dinv*agg(h2t) + b2
    {
        const int NT = (256 / 4) * 2;  // 128 nodes per block
        dense_kernel<32, 16, 4, false><<<(N + NT - 1) / NT, 256, 0, stream>>>(bufB, W2, dinv, h2t, nullptr, N);
        int tailidx = (out_size > N * OC) ? (N * OC) : -1;
        csr_agg16x2_kernel<false><<<g2, 256, 0, stream>>>(
            pse, srcsP, dinv, h2t, h2t, b2, outp, OC, g2, N, tailidx);
    }
}

// Round 9
// 182.336 us; speedup vs baseline: 1.2897x; 1.0527x over previous
//
#include <hip/hip_runtime.h>

// GCN 2-layer forward, fp32 in/out, fp16 gather tables. Build: 2-pass MSD
// radix sort by target node -> PADDED CSR (pad to mult of 16, pads -> row n
// of zeroed table; zero-degree nodes pse=(0,0), masked out).
// Layer-1 aggregate: ONE C=32 pass over a single 64B-row fp16 table
// (hA: N x 32 cols = 1 cache line/row). One wave per TWO nodes, 2 eo-groups
// of 32 lanes, 8 edges/node/step (1 int4 srcs + 4 gathers per node, each
// gather inst = 2 unique 64B rows). 2-deep rotation, per-node fmaf masks.
// Layer-2 aggregate: r19's C=16 kernel (32B rows), int4 srcs.
// History: r12 fp16 tables; r13 tail-split regressed; r14 split tables
// (FETCH 101->29/pass, time flat); r15 2-deep rotation; r16 2 nodes/wave
// 53.8us; r17/r18 regressed (depth, warm+nt) -> traffic irrelevant;
// r19 int4 srcs 16->10 VMEM/step gave only -6.5% -> bound is GATHER
// SEGMENT throughput (~4.8cy per unique-row address group, 6.4M lookups).
// r20 (this): fuse layer-1 to C=32/64B rows -> 3.2M lookups (each edge's
// row read ONCE). Same inst count, half the segments.

#define WAVE 64
#define BN2 512           // nodes per bucket (9 bits local col)
#define NBMAX 256         // max coarse buckets (N <= 131072)
#define CHUNK 8192        // edges per partition block

typedef _Float16 f16;

// ---- bucket count: global histogram of col>>9 ----
__global__ void bucket_count_kernel(const int* __restrict__ col, int* __restrict__ gcnt,
                                    int E, int nb) {
    __shared__ int h[NBMAX];
    for (int i = threadIdx.x; i < nb; i += blockDim.x) h[i] = 0;
    __syncthreads();
    for (int e = blockIdx.x * blockDim.x + threadIdx.x; e < E; e += gridDim.x * blockDim.x)
        atomicAdd(&h[col[e] >> 9], 1);
    __syncthreads();
    for (int i = threadIdx.x; i < nb; i += blockDim.x)
        if (h[i]) atomicAdd(&gcnt[i], h[i]);
}

// ---- exclusive scan of bucket counts -> bptr[nb+1], init gcursor/gpcur,
//      zero the dummy gather rows (row N of hA (32 cols) and h2t (16)) ----
__global__ void bucket_scan_kernel(const int* __restrict__ cnt, int* __restrict__ bptr,
                                   int* __restrict__ gcur, int nb, int* __restrict__ gpcur,
                                   f16* __restrict__ hA, f16* __restrict__ h2t, int nzr) {
    int lane = threadIdx.x;  // single wave
    if (lane == 0) gpcur[0] = 0;
    if (lane < 32)      hA[(size_t)nzr * 32 + lane]         = (f16)0.f;
    else if (lane < 48) h2t[(size_t)nzr * 16 + (lane - 32)] = (f16)0.f;
    int carry = 0;
    for (int base = 0; base < nb; base += WAVE) {
        int i = base + lane;
        int orig = (i < nb) ? cnt[i] : 0;
        int v = orig;
#pragma unroll
        for (int off = 1; off < WAVE; off <<= 1) {
            int t = __shfl_up(v, off, WAVE);
            if (lane >= off) v += t;
        }
        if (i < nb) { bptr[i] = carry + v - orig; gcur[i] = carry + v - orig; }
        carry += __shfl(v, WAVE - 1, WAVE);
    }
    if (lane == 0) bptr[nb] = carry;
}

// ---- pass 1: LDS-binned partition of packed (src<<9 | local_col) ----
__global__ void __launch_bounds__(512)
partition_kernel(const int* __restrict__ row, const int* __restrict__ col,
                 int* __restrict__ gcursor, unsigned* __restrict__ packed,
                 int E, int nb) {
    __shared__ int hist[NBMAX], excl[NBMAX], cursor[NBMAX], baseoff[NBMAX];
    __shared__ unsigned stage[CHUNK];
    int chunk0 = blockIdx.x * CHUNK;
    int cn = E - chunk0; if (cn > CHUNK) cn = CHUNK;
    for (int i = threadIdx.x; i < nb; i += blockDim.x) hist[i] = 0;
    __syncthreads();
    for (int i = threadIdx.x; i < cn; i += blockDim.x)
        atomicAdd(&hist[col[chunk0 + i] >> 9], 1);
    __syncthreads();
    if (threadIdx.x < WAVE) {
        int lane = threadIdx.x, carry = 0;
        for (int base = 0; base < nb; base += WAVE) {
            int i = base + lane;
            int orig = (i < nb) ? hist[i] : 0;
            int v = orig;
#pragma unroll
            for (int off = 1; off < WAVE; off <<= 1) {
                int t = __shfl_up(v, off, WAVE);
                if (lane >= off) v += t;
            }
            if (i < nb) { excl[i] = carry + v - orig; cursor[i] = carry + v - orig; }
            carry += __shfl(v, WAVE - 1, WAVE);
        }
    }
    __syncthreads();
    for (int b = threadIdx.x; b < nb; b += blockDim.x) {
        int c = hist[b];
        baseoff[b] = c ? atomicAdd(&gcursor[b], c) : 0;
    }
    __syncthreads();
    for (int i = threadIdx.x; i < cn; i += blockDim.x) {
        int c = col[chunk0 + i], r = row[chunk0 + i];
        int b = c >> 9;
        int pos = atomicAdd(&cursor[b], 1);
        stage[pos] = ((unsigned)r << 9) | (unsigned)(c & (BN2 - 1));
    }
    __syncthreads();
    int wave = threadIdx.x >> 6, lane = threadIdx.x & 63, nw = blockDim.x >> 6;
    for (int b = wave; b < nb; b += nw) {
        int c = hist[b]; if (!c) continue;
        int s = excl[b], d = baseoff[b];
        for (int k = lane; k < c; k += WAVE) packed[d + k] = stage[s + k];
    }
}

// ---- pass 2: per-bucket sort by local node -> padded srcs, pse, dinv.
//      Per-node region padded to multiple of 16; pads point at row n (zeros).
//      Zero-degree nodes get pse=(0,0). Bucket regions via global cursor. ----
__global__ void __launch_bounds__(512)
sort_kernel(const int* __restrict__ bptr, const unsigned* __restrict__ packed,
            int* __restrict__ srcs, int2* __restrict__ pse,
            float* __restrict__ dinv, int* __restrict__ gpcur,
            int n, int nb, int E) {
    __shared__ int hist[BN2], pex[BN2], cur[BN2];
    __shared__ int pbase_s;
    int b = blockIdx.x;
    int start = bptr[b], end = bptr[b + 1];
    for (int i = threadIdx.x; i < BN2; i += blockDim.x) { hist[i] = 0; cur[i] = 0; }
    __syncthreads();
    for (int k = start + threadIdx.x; k < end; k += blockDim.x)
        atomicAdd(&hist[packed[k] & (BN2 - 1)], 1);
    __syncthreads();
    if (threadIdx.x < WAVE) {   // scan of PADDED degrees over 512 locals
        int lane = threadIdx.x, carry = 0;
#pragma unroll
        for (int base = 0; base < BN2; base += WAVE) {
            int i = base + lane;
            int pd = (hist[i] + 15) & ~15;
            int v = pd;
#pragma unroll
            for (int off = 1; off < WAVE; off <<= 1) {
                int t = __shfl_up(v, off, WAVE);
                if (lane >= off) v += t;
            }
            pex[i] = carry + v - pd;
            carry += __shfl(v, WAVE - 1, WAVE);
        }
        if (lane == 0) pbase_s = atomicAdd(gpcur, carry);
    }
    __syncthreads();
    int pbase = pbase_s;
    for (int i = threadIdx.x; i < BN2; i += blockDim.x) {
        int node = b * BN2 + i;
        if (node < n) {
            int d = hist[i], pd = (d + 15) & ~15;
            int ps = pbase + pex[i];
            pse[node]  = d ? make_int2(ps, ps + pd) : make_int2(0, 0);
            dinv[node] = d ? rsqrtf((float)d) : 0.f;
            for (int k = d; k < pd; ++k) srcs[ps + k] = n;   // dummy zero-row
        }
    }
    __syncthreads();
    for (int k = start + threadIdx.x; k < end; k += blockDim.x) {
        unsigned p = packed[k];
        int lc = p & (BN2 - 1);
        int pos = atomicAdd(&cur[lc], 1);
        srcs[pbase + pex[lc] + pos] = (int)(p >> 9);
    }
}

// ---- dense: h[n,OUTC] = fp16( (x[n,INC] @ W) * dinv[n] ).
//      Thread = 2 nodes x 4 j. W^T in LDS, stride INC+4 (conflict-free). ----
template <int INC, int OUTC, int JT>
__global__ void __launch_bounds__(256, 4)
dense_kernel(const float* __restrict__ x, const float* __restrict__ W,
             const float* __restrict__ dinv, f16* __restrict__ h, int n) {
    const int LSTR = INC + 4;
    const int SP   = 256 / JT;     // node slots (pairs) per block
    const int NT   = SP * 2;       // nodes per block
    __shared__ float Wt[OUTC * LSTR];
    for (int i = threadIdx.x; i < INC * OUTC; i += 256) {
        int k = i / OUTC, j = i % OUTC;
        Wt[j * LSTR + k] = W[i];
    }
    __syncthreads();
    const int jg = threadIdx.x % JT;
    const int sp = threadIdx.x / JT;
    int base = blockIdx.x * NT;
    int n0 = base + sp;
    int n1 = base + sp + SP;
    int n0c = n0 < n ? n0 : n - 1;   // clamp reads, guard writes
    int n1c = n1 < n ? n1 : n - 1;
    const float4* xr0 = (const float4*)(x + (size_t)n0c * INC);
    const float4* xr1 = (const float4*)(x + (size_t)n1c * INC);
    float a[2][4] = {{0.f, 0.f, 0.f, 0.f}, {0.f, 0.f, 0.f, 0.f}};
#pragma unroll 4
    for (int k4 = 0; k4 < INC / 4; ++k4) {
        float4 v0 = xr0[k4];
        float4 v1 = xr1[k4];
#pragma unroll
        for (int u = 0; u < 4; ++u) {
            float4 w = *(const float4*)(Wt + (jg + u * JT) * LSTR + 4 * k4);
            a[0][u] = fmaf(v0.x, w.x, fmaf(v0.y, w.y, fmaf(v0.z, w.z, fmaf(v0.w, w.w, a[0][u]))));
            a[1][u] = fmaf(v1.x, w.x, fmaf(v1.y, w.y, fmaf(v1.z, w.z, fmaf(v1.w, w.w, a[1][u]))));
        }
    }
#pragma unroll
    for (int pair = 0; pair < 2; ++pair) {
        int nn = pair ? n1 : n0;
        if (nn < n) {
            float d = dinv[nn];
            f16* hr = h + (size_t)nn * OUTC;
#pragma unroll
            for (int u = 0; u < 4; ++u) hr[jg + u * JT] = (f16)(a[pair][u] * d);
        }
    }
}

// ---- layer-1 aggregate: one wave per TWO nodes; 32 lanes per 64B fp16 row
//      (1 cache line). 2 eo-groups; per node per step: 1 int4 srcs (8 edges)
//      + 4 gather insts (2 rows each). 2-deep rotation, per-node masks. ----
#define GLD32(s) (*(const f16*)(hb + (((unsigned)(s) << 6) + j2)))

template <bool RELU>
__global__ void __launch_bounds__(256)
csr_agg32x2_kernel(const int2* __restrict__ pse, const int* __restrict__ srcs,
                   const float* __restrict__ dinv, const f16* __restrict__ hs,
                   const float* __restrict__ bias, float* __restrict__ out,
                   int ostride, int n) {
    int lane = threadIdx.x & 63;
    int wid  = threadIdx.x >> 6;
    int j  = lane & 31;
    int eo = lane >> 5;           // 0..1
    int n0 = ((int)blockIdx.x * 4 + wid) * 2;
    if (n0 >= n) return;
    int n1 = n0 + 1;
    bool v1 = n1 < n;
    int4 se = *(const int4*)(pse + n0);      // pse[n0], pse[n1]
    int nb0 = (se.y - se.x) >> 3;            // blocks of 8 edges
    int nb1 = v1 ? ((se.w - se.z) >> 3) : 0;
    float dv0 = dinv[n0];
    float dv1 = v1 ? dinv[n1] : 0.f;
    float bj = bias[j];
    size_t ob0 = (size_t)n0 * ostride + j;
    size_t ob1 = (size_t)n1 * ostride + j;
    int MAXB = nb0 > nb1 ? nb0 : nb1;
    if (MAXB == 0) {
        float v = bj;
        if (RELU) v = v > 0.f ? v : 0.f;
        if (eo == 0) out[ob0] = v;
        else if (v1) out[ob1] = v;
        return;
    }
    const unsigned j2 = (unsigned)(j << 1);
    const char* hb = (const char*)hs;
    // region starts are multiples of 16 ints -> int4-aligned; step s,
    // group eo reads ints s*8 + eo*4 .. +3  ->  int4 index s*2 (P has +eo)
    const int4* P0 = (const int4*)(srcs + se.x) + eo;
    const int4* P1 = (const int4*)(srcs + (v1 ? se.z : se.x)) + eo;
    int nc0 = nb0 > 1 ? nb0 : 1;
    int nc1 = nb1 > 1 ? nb1 : 1;
    // prologue: block-0 srcs, block-0 gathers, block-1 srcs (clamped)
    int4 sA0 = P0[0];
    int4 sA1 = P1[0];
    f16 h0 = GLD32(sA0.x), h1 = GLD32(sA0.y), h2 = GLD32(sA0.z), h3 = GLD32(sA0.w);
    f16 h4 = GLD32(sA1.x), h5 = GLD32(sA1.y), h6 = GLD32(sA1.z), h7 = GLD32(sA1.w);
    int4 sB0 = P0[(nc0 > 1 ? 1 : 0) * 2];
    int4 sB1 = P1[(nc1 > 1 ? 1 : 0) * 2];
    float acc0 = 0.f, acc1 = 0.f, acc2 = 0.f, acc3 = 0.f;
    for (int b = 0; b < MAXB - 1; ++b) {
        // gathers for block b+1
        f16 g0 = GLD32(sB0.x), g1 = GLD32(sB0.y), g2 = GLD32(sB0.z), g3 = GLD32(sB0.w);
        f16 g4 = GLD32(sB1.x), g5 = GLD32(sB1.y), g6 = GLD32(sB1.z), g7 = GLD32(sB1.w);
        // srcs for block b+2 (clamped per node), one int4 per node
        int x0 = (b + 2) < nc0 ? (b + 2) : nc0 - 1;
        int x1 = (b + 2) < nc1 ? (b + 2) : nc1 - 1;
        int4 t0 = P0[x0 * 2];
        int4 t1 = P1[x1 * 2];
        // consume block b (masked per node)
        float m0 = b < nb0 ? 1.f : 0.f;
        float m1 = b < nb1 ? 1.f : 0.f;
        acc0 = fmaf(m0, (float)h0, acc0);
        acc1 = fmaf(m0, (float)h1, acc1);
        acc0 = fmaf(m0, (float)h2, acc0);
        acc1 = fmaf(m0, (float)h3, acc1);
        acc2 = fmaf(m1, (float)h4, acc2);
        acc3 = fmaf(m1, (float)h5, acc3);
        acc2 = fmaf(m1, (float)h6, acc2);
        acc3 = fmaf(m1, (float)h7, acc3);
        h0 = g0; h1 = g1; h2 = g2; h3 = g3;
        h4 = g4; h5 = g5; h6 = g6; h7 = g7;
        sB0 = t0; sB1 = t1;
    }
    {   // epilogue: block MAXB-1
        float m0 = (MAXB - 1) < nb0 ? 1.f : 0.f;
        float m1 = (MAXB - 1) < nb1 ? 1.f : 0.f;
        acc0 = fmaf(m0, (float)h0, acc0);
        acc1 = fmaf(m0, (float)h1, acc1);
        acc0 = fmaf(m0, (float)h2, acc0);
        acc1 = fmaf(m0, (float)h3, acc1);
        acc2 = fmaf(m1, (float)h4, acc2);
        acc3 = fmaf(m1, (float)h5, acc3);
        acc2 = fmaf(m1, (float)h6, acc2);
        acc3 = fmaf(m1, (float)h7, acc3);
    }
    float accA = acc0 + acc1;  // node0
    float accB = acc2 + acc3;  // node1
    accA += __shfl_xor(accA, 32, WAVE);   // combine the two eo-groups
    accB += __shfl_xor(accB, 32, WAVE);
    if (eo == 0) {
        float v = accA * dv0 + bj;
        if (RELU) v = v > 0.f ? v : 0.f;
        out[ob0] = v;
    } else if (v1) {
        float v = accB * dv1 + bj;
        if (RELU) v = v > 0.f ? v : 0.f;
        out[ob1] = v;
    }
}

// ---- layer-2 aggregate: C=16 (32B rows), int4 srcs, 2-deep rotation. ----
#define GLD16(s) (*(const f16*)(hb + (((unsigned)(s) << 5) + j2)))

template <bool RELU>
__global__ void __launch_bounds__(256)
csr_agg16x2_kernel(const int2* __restrict__ pse, const int* __restrict__ srcs,
                   const float* __restrict__ dinv, const f16* __restrict__ hs,
                   const float* __restrict__ bias, float* __restrict__ out,
                   int ostride, int n, int tailidx) {
    int bid = blockIdx.x;
    int lane = threadIdx.x & 63;
    int wid  = threadIdx.x >> 6;
    int j  = lane & 15;
    int eo = lane >> 4;           // 0..3
    if (tailidx >= 0 && bid == 0 && threadIdx.x == 0) out[tailidx] = 0.f;
    int n0 = (bid * 4 + wid) * 2;
    if (n0 >= n) return;
    int n1 = n0 + 1;
    bool v1 = n1 < n;
    int4 se = *(const int4*)(pse + n0);      // pse[n0], pse[n1]
    int nb0 = (se.y - se.x) >> 4;
    int nb1 = v1 ? ((se.w - se.z) >> 4) : 0;
    float dv0 = dinv[n0];
    float dv1 = v1 ? dinv[n1] : 0.f;
    float bj = bias[j];
    size_t ob0 = (size_t)n0 * ostride + j;
    size_t ob1 = (size_t)n1 * ostride + j;
    int MAXB = nb0 > nb1 ? nb0 : nb1;
    if (MAXB == 0) {
        float v = bj;
        if (RELU) v = v > 0.f ? v : 0.f;
        if (eo == 0) out[ob0] = v;
        else if (eo == 1 && v1) out[ob1] = v;
        return;
    }
    const unsigned j2 = (unsigned)(j << 1);
    const char* hb = (const char*)hs;
    const int4* P0 = (const int4*)(srcs + se.x) + eo;
    const int4* P1 = (const int4*)(srcs + (v1 ? se.z : se.x)) + eo;
    int nc0 = nb0 > 1 ? nb0 : 1;
    int nc1 = nb1 > 1 ? nb1 : 1;
    int4 sA0 = P0[0];
    int4 sA1 = P1[0];
    f16 h0 = GLD16(sA0.x), h1 = GLD16(sA0.y), h2 = GLD16(sA0.z), h3 = GLD16(sA0.w);
    f16 h4 = GLD16(sA1.x), h5 = GLD16(sA1.y), h6 = GLD16(sA1.z), h7 = GLD16(sA1.w);
    int4 sB0 = P0[(nc0 > 1 ? 1 : 0) * 4];
    int4 sB1 = P1[(nc1 > 1 ? 1 : 0) * 4];
    float acc0 = 0.f, acc1 = 0.f, acc2 = 0.f, acc3 = 0.f;
    for (int b = 0; b < MAXB - 1; ++b) {
        f16 g0 = GLD16(sB0.x), g1 = GLD16(sB0.y), g2 = GLD16(sB0.z), g3 = GLD16(sB0.w);
        f16 g4 = GLD16(sB1.x), g5 = GLD16(sB1.y), g6 = GLD16(sB1.z), g7 = GLD16(sB1.w);
        int x0 = (b + 2) < nc0 ? (b + 2) : nc0 - 1;
        int x1 = (b + 2) < nc1 ? (b + 2) : nc1 - 1;
        int4 t0 = P0[x0 * 4];
        int4 t1 = P1[x1 * 4];
        float m0 = b < nb0 ? 1.f : 0.f;
        float m1 = b < nb1 ? 1.f : 0.f;
        acc0 = fmaf(m0, (float)h0, acc0);
        acc1 = fmaf(m0, (float)h1, acc1);
        acc0 = fmaf(m0, (float)h2, acc0);
        acc1 = fmaf(m0, (float)h3, acc1);
        acc2 = fmaf(m1, (float)h4, acc2);
        acc3 = fmaf(m1, (float)h5, acc3);
        acc2 = fmaf(m1, (float)h6, acc2);
        acc3 = fmaf(m1, (float)h7, acc3);
        h0 = g0; h1 = g1; h2 = g2; h3 = g3;
        h4 = g4; h5 = g5; h6 = g6; h7 = g7;
        sB0 = t0; sB1 = t1;
    }
    {
        float m0 = (MAXB - 1) < nb0 ? 1.f : 0.f;
        float m1 = (MAXB - 1) < nb1 ? 1.f : 0.f;
        acc0 = fmaf(m0, (float)h0, acc0);
        acc1 = fmaf(m0, (float)h1, acc1);
        acc0 = fmaf(m0, (float)h2, acc0);
        acc1 = fmaf(m0, (float)h3, acc1);
        acc2 = fmaf(m1, (float)h4, acc2);
        acc3 = fmaf(m1, (float)h5, acc3);
        acc2 = fmaf(m1, (float)h6, acc2);
        acc3 = fmaf(m1, (float)h7, acc3);
    }
    float accA = acc0 + acc1;  // node0
    float accB = acc2 + acc3;  // node1
    accA += __shfl_xor(accA, 16, WAVE);
    accA += __shfl_xor(accA, 32, WAVE);
    accB += __shfl_xor(accB, 16, WAVE);
    accB += __shfl_xor(accB, 32, WAVE);
    if (eo == 0) {
        float v = accA * dv0 + bj;
        if (RELU) v = v > 0.f ? v : 0.f;
        out[ob0] = v;
    } else if (eo == 1 && v1) {
        float v = accB * dv1 + bj;
        if (RELU) v = v > 0.f ? v : 0.f;
        out[ob1] = v;
    }
}

extern "C" void kernel_launch(void* const* d_in, const int* in_sizes, int n_in,
                              void* d_out, int out_size, void* d_ws, size_t ws_size,
                              hipStream_t stream) {
    const float* x  = (const float*)d_in[0];
    const int*   ei = (const int*)d_in[1];    // harness converts int64 -> int32
    const float* W1 = (const float*)d_in[2];
    const float* b1 = (const float*)d_in[3];
    const float* W2 = (const float*)d_in[4];
    const float* b2 = (const float*)d_in[5];

    const int IN_C = 128, HID = 32, OC = 16;
    const int N = in_sizes[0] / IN_C;       // 100000
    const int E = in_sizes[1] / 2;          // 3200000
    const int* row = ei;
    const int* col = ei + E;
    const int NB = (N + BN2 - 1) / BN2;     // 196 coarse buckets

    char* base = (char*)d_ws;
    size_t off = 0;
    auto carve = [&](size_t bytes) -> char* {
        char* p = base + off;
        off = (off + bytes + 255) & ~(size_t)255;
        return p;
    };
    int*      gcnt  = (int*)     carve((size_t)NB * 4);
    int*      bptr  = (int*)     carve((size_t)(NB + 1) * 4);
    int*      gcur  = (int*)     carve((size_t)NB * 4);
    int*      gpcur = (int*)     carve(8);
    float*    dinv  = (float*)   carve((size_t)N * 4);
    int2*     pse   = (int2*)    carve((size_t)(N + 2) * 8);
    unsigned* packed= (unsigned*)carve((size_t)E * 4);
    int*      srcsP = (int*)     carve(((size_t)E + (size_t)N * 32 + 256) * 4); // pads + slack
    f16*      hA    = (f16*)     carve((size_t)(N + 1) * 32 * 2);  // layer1 table, 64B rows (+zero row)
    f16*      h2t   = (f16*)     carve((size_t)(N + 1) * 16 * 2);  // layer2 table (+zero row)
    float*    bufB  = (float*)   carve((size_t)N * HID * 4);       // relu(agg1), fp32
    (void)ws_size; (void)n_in;

    float* outp = (float*)d_out;

    // build: 2-pass coarse radix sort by target node -> padded CSR + dinv
    hipMemsetAsync(gcnt, 0, (size_t)NB * 4, stream);
    bucket_count_kernel<<<512, 256, 0, stream>>>(col, gcnt, E, NB);
    bucket_scan_kernel<<<1, 64, 0, stream>>>(gcnt, bptr, gcur, NB, gpcur, hA, h2t, N);
    partition_kernel<<<(E + CHUNK - 1) / CHUNK, 512, 0, stream>>>(row, col, gcur, packed, E, NB);
    sort_kernel<<<NB, 512, 0, stream>>>(bptr, packed, srcsP, pse, dinv, gpcur, N, NB, E);

    int npb = 8;                         // 4 waves x 2 nodes per block
    int g2  = (N + npb - 1) / npb;       // 12500 blocks

    // layer 1: hA = fp16((x@W1)*dinv) ; bufB = relu(dinv*agg(hA) + b1)
    {
        const int NT = (256 / 8) * 2;  // 64 nodes per block
        dense_kernel<128, 32, 8><<<(N + NT - 1) / NT, 256, 0, stream>>>(x, W1, dinv, hA, N);
        csr_agg32x2_kernel<true><<<g2, 256, 0, stream>>>(
            pse, srcsP, dinv, hA, b1, bufB, HID, N);
    }
    // layer 2: h2t = fp16((bufB@W2)*dinv) ; out = dinv*agg(h2t) + b2
    {
        const int NT = (256 / 4) * 2;  // 128 nodes per block
        dense_kernel<32, 16, 4><<<(N + NT - 1) / NT, 256, 0, stream>>>(bufB, W2, dinv, h2t, N);
        int tailidx = (out_size > N * OC) ? (N * OC) : -1;
        csr_agg16x2_kernel<false><<<g2, 256, 0, stream>>>(
            pse, srcsP, dinv, h2t, b2, outp, OC, N, tailidx);
    }
}